// Round 14
// baseline (583.420 us; speedup 1.0000x reference)
//
#include <hip/hip_runtime.h>
#include <hip/hip_bf16.h>

typedef __bf16 bf16x8 __attribute__((ext_vector_type(8)));
typedef float  f32x4  __attribute__((ext_vector_type(4)));

#define MFMA(a,b,c) __builtin_amdgcn_mfma_f32_16x16x32_bf16((a),(b),(c),0,0,0)

// problem constants
#define NN_  42
#define E_   41
#define FB_  4096
#define SCALE_ 0.17677669529663687f  // 1/sqrt(32)

// ws layout, element offsets into __bf16* ws
#define WB_WIN  0         // [128][32]
#define WB_QKV  4096      // [L][384][128]
#define WB_AO   102400    // [L][128][128]
#define WB_FF1  135168    // [L][256][128]
#define WB_FF2  200704    // [L][128][256]
#define WB_WOUT 266240    // [128][5376]
#define WB_X    954368    // [4096][5376] staged x_final (bf16)
#define PREP_N  954368

// === 2 TREES / 512 THREADS: one (head,tree) pair per wave ===
// r13 (2 trees, 4 waves) = 335us at 8 waves/CU (2/SIMD) — latency-bound with ~85% wave
// idle and ~84 unused regs/wave. This round: 8 waves/block (w8: h=w8&3, t=w8>>2) at the
// SAME LDS (81408 -> 2 blocks/CU) -> 16 waves/CU (4/SIMD). Reg budget 128/wave at
// (512,4); demand trimmed via r9's P-through-LDS attention (dwp[18]+PV-A-shuffles
// deleted; r9/r10-verified): est ~115-130. Per-wave work = r8 shape (3 row-tiles).
// Spill gate: WRITE_SIZE==43008 exactly; crush (VGPR<=64) => revert to r13.
// smem (bytes), total 81408:
//  [0,55296)      per-(head,tree) slab qk[48][72] (q 0..31, k 32..63), w8*6912
//                 P_lds [48][48] bf16 @slab base (post-scores; qk dead)
//                 aliases (lifetime-disjoint):
//                   fbf [96][40]          @0      (init/embed; 7680 B)
//                   bits int[96][4]       @7680   (init/embed)
//                   adj int[246]          @9216   (init)
//                   depth int[96]         @10200  (init)
//                   hbf [96][264]         @0      (FF only; 50688 B)
//                   part float[4][96][2]  @50688  (ln only; slab-7 P dead post-obf)
//                   statsA/B float[96]    @53760/54144
//  [55296,81408)  xbf/obf [96][136] bf16 (aliased; pre-obf barrier guards swap)
#define SM_SZ 81408

// ---------------- weight cast to bf16 ----------------
__global__ void prep_bf16(const float* __restrict__ W_in, const float* __restrict__ qkv_w,
                          const float* __restrict__ ao_w, const float* __restrict__ ff1_w,
                          const float* __restrict__ ff2_w, const float* __restrict__ W_out,
                          __bf16* __restrict__ wb) {
  int i = blockIdx.x * 256 + threadIdx.x;
  float v;
  if      (i < 4096)   v = W_in[i];
  else if (i < 102400) v = qkv_w[i - 4096];
  else if (i < 135168) v = ao_w[i - 102400];
  else if (i < 200704) v = ff1_w[i - 135168];
  else if (i < 266240) v = ff2_w[i - 200704];
  else if (i < 954368) v = W_out[i - 266240];
  else return;
  wb[i] = (__bf16)v;
}

__device__ __forceinline__ bf16x8 ld8(const __bf16* p) { return *(const bf16x8*)p; }

__device__ __forceinline__ int pack2(float a, float b) {
  union { __bf16 h[2]; int i; } u;
  u.h[0] = (__bf16)a; u.h[1] = (__bf16)b;
  return u.i;
}

// C = A[48xK] * B^T for NB column-tiles; A in LDS (lda halfwords), 3 row-tiles at rt*16.
template <int NB, int KS>
__device__ __forceinline__ void gemm3xN(const __bf16* A, int lda, const __bf16* const (&B)[NB],
                                        int c16, int quad, f32x4 (&acc)[NB][3]) {
#pragma unroll
  for (int i = 0; i < NB; ++i) {
    acc[i][0] = f32x4{0,0,0,0}; acc[i][1] = f32x4{0,0,0,0}; acc[i][2] = f32x4{0,0,0,0};
  }
#pragma unroll
  for (int ks = 0; ks < KS; ++ks) {
    int ko = ks * 32 + quad * 8;
    bf16x8 a0 = ld8(A + c16 * lda + ko);
    bf16x8 a1 = ld8(A + (16 + c16) * lda + ko);
    bf16x8 a2 = ld8(A + (32 + c16) * lda + ko);
#pragma unroll
    for (int i = 0; i < NB; ++i) {
      bf16x8 b = ld8(B[i] + ko);
      acc[i][0] = MFMA(a0, b, acc[i][0]);
      acc[i][1] = MFMA(a1, b, acc[i][1]);
      acc[i][2] = MFMA(a2, b, acc[i][2]);
    }
  }
}

// LayerNorm over 96 rows; wave (h,t) owns rows t*48+rloc, cols (2h+nt)*16+c16. 3 barriers.
__device__ __forceinline__ void ln_update(float (&res)[3][2][4], const float* __restrict__ g,
                                          const float* __restrict__ bb, __bf16* xbf, float* part,
                                          float* statsA, float* statsB, int tid, int h, int t,
                                          int c16, int quad) {
#pragma unroll
  for (int mt = 0; mt < 3; ++mt)
#pragma unroll
    for (int r = 0; r < 4; ++r) {
      float s = res[mt][0][r] + res[mt][1][r];
      float ss = res[mt][0][r] * res[mt][0][r] + res[mt][1][r] * res[mt][1][r];
      s += __shfl_xor(s, 1); ss += __shfl_xor(ss, 1);
      s += __shfl_xor(s, 2); ss += __shfl_xor(ss, 2);
      s += __shfl_xor(s, 4); ss += __shfl_xor(ss, 4);
      s += __shfl_xor(s, 8); ss += __shfl_xor(ss, 8);
      if (c16 == 0) {
        int rowg = t * 48 + mt * 16 + quad * 4 + r;
        part[(h * 96 + rowg) * 2] = s; part[(h * 96 + rowg) * 2 + 1] = ss;
      }
    }
  __syncthreads();
  if (tid < 96) {
    float S = 0.f, SS = 0.f;
#pragma unroll
    for (int h2 = 0; h2 < 4; ++h2) { S += part[(h2 * 96 + tid) * 2]; SS += part[(h2 * 96 + tid) * 2 + 1]; }
    float mu = S * 0.0078125f;
    float var = fmaxf(SS * 0.0078125f - mu * mu, 0.f);
    statsA[tid] = mu; statsB[tid] = rsqrtf(var + 1e-5f);
  }
  __syncthreads();
  float gg[2], bv[2];
#pragma unroll
  for (int nt = 0; nt < 2; ++nt) { int col = (2 * h + nt) * 16 + c16; gg[nt] = g[col]; bv[nt] = bb[col]; }
#pragma unroll
  for (int mt = 0; mt < 3; ++mt)
#pragma unroll
    for (int r = 0; r < 4; ++r) {
      int rloc = mt * 16 + quad * 4 + r;
      int rowg = t * 48 + rloc;
      float mu = statsA[rowg], rs = statsB[rowg];
#pragma unroll
      for (int nt = 0; nt < 2; ++nt) {
        float v = (res[mt][nt][r] - mu) * rs * gg[nt] + bv[nt];
        res[mt][nt][r] = v;
        xbf[rowg * 136 + (2 * h + nt) * 16 + c16] = (__bf16)(rloc < NN_ ? v : 0.f);
      }
    }
  __syncthreads();
}

// ---------------- per-block fused encoder: 2 trees x 4 heads = 8 waves ----------------
__global__ __launch_bounds__(512, 4) void tree_enc(
    const float* __restrict__ forest, const int* __restrict__ adjacency,
    const int* __restrict__ node_order, const float* __restrict__ b_in,
    const float* __restrict__ qkv_b, const float* __restrict__ ao_b,
    const float* __restrict__ ff1_b, const float* __restrict__ ff2_b,
    const float* __restrict__ ln1_g, const float* __restrict__ ln1_b,
    const float* __restrict__ ln2_g, const float* __restrict__ ln2_b,
    const __bf16* __restrict__ wb, __bf16* __restrict__ Xg) {
  const int f0 = blockIdx.x * 2, tid = threadIdx.x;
  const int lane = tid & 63, w8 = tid >> 6;   // wave 0..7
  const int h = w8 & 3, t = w8 >> 2;          // head, tree
  const int c16 = lane & 15, quad = lane >> 4;

  __shared__ alignas(16) unsigned char smem[SM_SZ];
  __bf16* qk     = (__bf16*)(smem + w8 * 6912);  // per-(head,tree) [48][72]; P_lds [48][48]
  __bf16* fbf    = (__bf16*)smem;                // [96][40] (init only)
  __bf16* hbf    = (__bf16*)smem;                // [96][264] (FF only)
  int*    bits_s = (int*)(smem + 7680);          // [96][4]
  int*    adj_s  = (int*)(smem + 9216);          // [246]
  int*    depth_s= (int*)(smem + 10200);         // [96]
  float*  part   = (float*)(smem + 50688);       // ln only
  float*  statsA = (float*)(smem + 53760);
  float*  statsB = (float*)(smem + 54144);
  __bf16* xbf    = (__bf16*)(smem + 55296);      // [96][136] x / attn-o (aliased)

  // ---- init phase 1: zeros (fbf + bits), adjacency, depths ----
  for (int i = tid; i < 2304; i += 512) ((int*)smem)[i] = 0;
  if (tid < 246) adj_s[tid] = adjacency[f0 * (E_ * 3) + tid];
  if (w8 == 2 || w8 == 3) {
    int t2 = w8 - 2;
    int v = (lane < NN_) ? node_order[(f0 + t2) * NN_ + lane] : 0;
    int mx = v;
#pragma unroll
    for (int m = 1; m < 64; m <<= 1) mx = max(mx, __shfl_xor(mx, m));
    if (lane < 48) depth_s[t2 * 48 + lane] = (lane < NN_) ? (mx - v) : 0;
  }
  __syncthreads();

  // ---- init phase 2: stage forest bf16 + positional walks (wave t handles tree t) ----
  for (int i = tid; i < 2688; i += 512) {
    int tree = i >= 1344 ? 1 : 0;
    int j = i - tree * 1344;
    fbf[(tree * 48 + (j >> 5)) * 40 + (j & 31)] = (__bf16)forest[(f0 + tree) * 1344 + j];
  }
  if (w8 < 2) {
    const int tt = w8;
    int pl = -1, cl = 0, pd = 0, idx = 0;
    if (lane < E_) {
      int p = adj_s[tt * 123 + lane * 3], c = adj_s[tt * 123 + lane * 3 + 1],
          s = adj_s[tt * 123 + lane * 3 + 2];
      if (p >= 0 && c >= 0) {
        pl = p - (f0 + tt) * NN_; cl = c - (f0 + tt) * NN_;
        int si = s + 1; si = si < 0 ? 0 : (si > 2 ? 2 : si);
        pd = depth_s[tt * 48 + pl]; idx = pd * 3 + si;
      }
    }
    int dv = (lane < NN_) ? depth_s[tt * 48 + lane] : 0;
#pragma unroll
    for (int m = 1; m < 64; m <<= 1) dv = max(dv, __shfl_xor(dv, m));
    int plc = tt * 48 + (pl < 0 ? 0 : pl);
    int clr = tt * 48 + cl;
    int bm = 1 << (idx & 31), wi = idx >> 5;
    int m0 = (wi == 0) ? bm : 0, m1 = (wi == 1) ? bm : 0;
    int m2 = (wi == 2) ? bm : 0, m3 = (wi == 3) ? bm : 0;
    for (int d = 0; d < dv; ++d) {
      int4 pb = *(int4*)&bits_s[plc * 4];
      if (pl >= 0 && pd == d) {
        int4 nb;
        nb.x = pb.x | m0; nb.y = pb.y | m1; nb.z = pb.z | m2; nb.w = pb.w | m3;
        *(int4*)&bits_s[clr * 4] = nb;
      }
      asm volatile("s_waitcnt lgkmcnt(0)" ::: "memory");
    }
  }
  __syncthreads();

  // ---- embed: x0 = forest @ W_in^T + b_in + pos (wave handles its tree rows, head cols) ----
  float res[3][2][4];
  {
    const __bf16* Bw[2] = { wb + WB_WIN + ((2 * h) * 16 + c16) * 32,
                            wb + WB_WIN + ((2 * h + 1) * 16 + c16) * 32 };
    f32x4 ea[2][3];
    gemm3xN<2, 1>(fbf + t * 48 * 40, 40, Bw, c16, quad, ea);
#pragma unroll
    for (int nt = 0; nt < 2; ++nt) {
      int col = (2 * h + nt) * 16 + c16;
      float bi = b_in[col];
      int wsel = col >> 5, shv = col & 31;
#pragma unroll
      for (int mt = 0; mt < 3; ++mt)
#pragma unroll
        for (int r = 0; r < 4; ++r) {
          int rloc = mt * 16 + quad * 4 + r;
          int rowg = t * 48 + rloc;
          float v = ea[nt][mt][r] + bi + (float)((bits_s[rowg * 4 + wsel] >> shv) & 1);
          res[mt][nt][r] = v;
          xbf[rowg * 136 + col] = (__bf16)(rloc < NN_ ? v : 0.f);
        }
    }
  }
  __syncthreads();

  // ---- encoder layers ----
  for (int l = 0; l < 2; ++l) {
    // === per-wave qkv GEMM (head h, tree t); three 2-tile passes ===
    int vp[2][3][2];  // [d-half][node m-tile][node pair]
    {
      const __bf16* qkvW = wb + WB_QKV + l * 384 * 128;
      const float* qbl = qkv_b + l * 384;
#pragma unroll
      for (int p = 0; p < 3; ++p) {  // 0=Q, 1=K, 2=V
        f32x4 qa[2][3];
        const __bf16* Bp[2];
#pragma unroll
        for (int j = 0; j < 2; ++j)
          Bp[j] = qkvW + (p * 128 + h * 32 + j * 16 + c16) * 128;
        gemm3xN<2, 4>(xbf + t * 48 * 136, 136, Bp, c16, quad, qa);
#pragma unroll
        for (int j = 0; j < 2; ++j) {
          float bias = qbl[p * 128 + h * 32 + j * 16 + c16];
#pragma unroll
          for (int mt = 0; mt < 3; ++mt) {
            if (p == 2) {  // V -> registers (bf16 pair-packed)
              vp[j][mt][0] = pack2(qa[j][mt][0] + bias, qa[j][mt][1] + bias);
              vp[j][mt][1] = pack2(qa[j][mt][2] + bias, qa[j][mt][3] + bias);
            } else {       // Q (scaled) / K -> wave-private slab
              int colo = (p == 0 ? 0 : 32) + j * 16 + c16;
#pragma unroll
              for (int r = 0; r < 4; ++r) {
                float v = qa[j][mt][r] + bias;
                if (p == 0) v *= SCALE_;
                qk[(mt * 16 + quad * 4 + r) * 72 + colo] = (__bf16)v;
              }
            }
          }
        }
      }
    }
    // NO barrier: scores/softmax/PV touch only the wave-private slab + registers.

    // === scores S^T = K Q^T, 9 tiles in-register ===
    f32x4 st[3][3];
    {
      bf16x8 ka[3], qb2[3];
#pragma unroll
      for (int m = 0; m < 3; ++m) ka[m] = ld8(qk + (m * 16 + c16) * 72 + 32 + quad * 8);
#pragma unroll
      for (int n = 0; n < 3; ++n) qb2[n] = ld8(qk + (n * 16 + c16) * 72 + quad * 8);
#pragma unroll
      for (int m = 0; m < 3; ++m)
#pragma unroll
        for (int n = 0; n < 3; ++n) {
          f32x4 z{0,0,0,0};
          st[m][n] = MFMA(ka[m], qb2[n], z);
        }
    }

    // === softmax in-register -> P to slab (qk dead post-scores); r9-verified pattern ===
#pragma unroll
    for (int n = 0; n < 3; ++n) {
      float mx = -3.0e38f;
#pragma unroll
      for (int m = 0; m < 3; ++m)
#pragma unroll
        for (int r = 0; r < 4; ++r) {
          bool valid = (m < 2) || (quad * 4 + r < 10);  // key < 42
          mx = fmaxf(mx, valid ? st[m][n][r] : -3.0e38f);
        }
      mx = fmaxf(mx, __shfl_xor(mx, 16));
      mx = fmaxf(mx, __shfl_xor(mx, 32));
      float sm = 0.f, ev[3][4];
#pragma unroll
      for (int m = 0; m < 3; ++m)
#pragma unroll
        for (int r = 0; r < 4; ++r) {
          bool valid = (m < 2) || (quad * 4 + r < 10);
          float e = valid ? __expf(st[m][n][r] - mx) : 0.f;
          ev[m][r] = e; sm += e;
        }
      sm += __shfl_xor(sm, 16);
      sm += __shfl_xor(sm, 32);
      float inv = 1.f / sm;
#pragma unroll
      for (int m = 0; m < 3; ++m) {
        int2 pw;
        pw.x = pack2(ev[m][0] * inv, ev[m][1] * inv);
        pw.y = pack2(ev[m][2] * inv, ev[m][3] * inv);
        *(int2*)(qk + (n * 16 + c16) * 48 + m * 16 + quad * 4) = pw;
      }
    }

    // === PV: A = P from slab (b128), V^T via vp shuffle-transpose ===
    f32x4 ov[3][2];
#pragma unroll
    for (int mtq = 0; mtq < 3; ++mtq) { ov[mtq][0] = f32x4{0,0,0,0}; ov[mtq][1] = f32x4{0,0,0,0}; }
    const bf16x8 zero8 = {0, 0, 0, 0, 0, 0, 0, 0};
#pragma unroll
    for (int ks = 0; ks < 2; ++ks) {
      bf16x8 bv[2];
#pragma unroll
      for (int nt = 0; nt < 2; ++nt) {
        union { int i[4]; bf16x8 v; } U;
#pragma unroll
        for (int m = 0; m < 4; ++m) {
          int srcl = (((quad << 1) + (m >> 1)) & 3) * 16 + c16;
          if (ks == 0) {
            int x0 = __shfl(vp[nt][0][m & 1], srcl);
            int x1 = __shfl(vp[nt][1][m & 1], srcl);
            U.i[m] = (quad >> 1) ? x1 : x0;
          } else {
            U.i[m] = __shfl(vp[nt][2][m & 1], srcl);
          }
        }
        bv[nt] = U.v;
      }
      bool zeroA = (ks == 1) && (quad > 1);
      int koA = zeroA ? 32 : (32 * ks + quad * 8);
#pragma unroll
      for (int mtq = 0; mtq < 3; ++mtq) {
        bf16x8 av = ld8(qk + (mtq * 16 + c16) * 48 + koA);
        if (zeroA) av = zero8;
        ov[mtq][0] = MFMA(av, bv[0], ov[mtq][0]);
        ov[mtq][1] = MFMA(av, bv[1], ov[mtq][1]);
      }
    }
    __syncthreads();  // all waves done reading xbf (qkv) before overwrite as obf
    // obf (= xbf alias) write: rows t*48.., cols h*32..
#pragma unroll
    for (int mtq = 0; mtq < 3; ++mtq)
#pragma unroll
      for (int nt = 0; nt < 2; ++nt)
#pragma unroll
        for (int r = 0; r < 4; ++r) {
          int rloc = mtq * 16 + quad * 4 + r;
          xbf[(t * 48 + rloc) * 136 + h * 32 + nt * 16 + c16] =
              (__bf16)(rloc < NN_ ? ov[mtq][nt][r] : 0.f);
        }
    __syncthreads();

    // === attn-out + residual ===
    {
      const __bf16* aoW = wb + WB_AO + l * 128 * 128;
      const __bf16* Bs[2] = { aoW + ((2 * h) * 16 + c16) * 128, aoW + ((2 * h + 1) * 16 + c16) * 128 };
      f32x4 aa[2][3];
      gemm3xN<2, 4>(xbf + t * 48 * 136, 136, Bs, c16, quad, aa);
#pragma unroll
      for (int nt = 0; nt < 2; ++nt) {
        float ab = ao_b[l * 128 + (2 * h + nt) * 16 + c16];
#pragma unroll
        for (int mt = 0; mt < 3; ++mt)
#pragma unroll
          for (int r = 0; r < 4; ++r) res[mt][nt][r] += aa[nt][mt][r] + ab;
      }
    }
    ln_update(res, ln1_g + l * 128, ln1_b + l * 128, xbf, part, statsA, statsB, tid, h, t, c16, quad);

    // === FF1 -> hbf (relu, bf16); two 2-tile passes ===
    {
      const __bf16* f1W = wb + WB_FF1 + l * 256 * 128;
#pragma unroll
      for (int pass = 0; pass < 2; ++pass) {
        const __bf16* Bs[2] = { f1W + ((4 * h + 2 * pass) * 16 + c16) * 128,
                                f1W + ((4 * h + 2 * pass + 1) * 16 + c16) * 128 };
        f32x4 fa[2][3];
        gemm3xN<2, 4>(xbf + t * 48 * 136, 136, Bs, c16, quad, fa);
#pragma unroll
        for (int j = 0; j < 2; ++j) {
          int nt = 2 * pass + j;
          int col = (4 * h + nt) * 16 + c16;
          float b1 = ff1_b[l * 256 + col];
#pragma unroll
          for (int mt = 0; mt < 3; ++mt)
#pragma unroll
            for (int r = 0; r < 4; ++r) {
              int rloc = mt * 16 + quad * 4 + r;
              float v = fmaxf(fa[j][mt][r] + b1, 0.f);
              hbf[(t * 48 + rloc) * 264 + col] = (__bf16)(rloc < NN_ ? v : 0.f);
            }
        }
      }
    }
    __syncthreads();

    // === FF2 + residual ===
    {
      const __bf16* f2W = wb + WB_FF2 + l * 128 * 256;
      const __bf16* Bs[2] = { f2W + ((2 * h) * 16 + c16) * 256, f2W + ((2 * h + 1) * 16 + c16) * 256 };
      f32x4 fa[2][3];
      gemm3xN<2, 8>(hbf + t * 48 * 264, 264, Bs, c16, quad, fa);
#pragma unroll
      for (int nt = 0; nt < 2; ++nt) {
        float fb2 = ff2_b[l * 128 + (2 * h + nt) * 16 + c16];
#pragma unroll
        for (int mt = 0; mt < 3; ++mt)
#pragma unroll
          for (int r = 0; r < 4; ++r) res[mt][nt][r] += fa[nt][mt][r] + fb2;
      }
    }
    ln_update(res, ln2_g + l * 128, ln2_b + l * 128, xbf, part, statsA, statsB, tid, h, t, c16, quad);
  }

  // ---- stage out: x_final (bf16) -> ws X, both trees ----
  {
    for (int c = tid; c < 1344; c += 512) {
      int tree = c >= 672 ? 1 : 0;
      int cc = c - tree * 672;
      int row = cc >> 4, co = (cc & 15) * 8;
      __bf16* Xf = Xg + (size_t)(f0 + tree) * 5376;
      *(bf16x8*)(Xf + row * 128 + co) = ld8(xbf + (tree * 48 + row) * 136 + co);
    }
  }
}

// ---------------- output projection + final LN, K split 4-way, 6-deep pipeline ----------------
__global__ __launch_bounds__(1024) void wout_k(const __bf16* __restrict__ X,
                                               const __bf16* __restrict__ Wb,
                                               const float* __restrict__ b_out,
                                               const float* __restrict__ lnf_g,
                                               const float* __restrict__ lnf_b,
                                               float* __restrict__ out) {
  const int blk = blockIdx.x, tid = threadIdx.x;
  const int lane = tid & 63, w2 = tid >> 6, wc = w2 & 3, kh = w2 >> 2;  // wc 0..3, kh 0..3
  const int c16 = lane & 15, quad = lane >> 4;
  __shared__ float cout[64 * 132];
  f32x4 acc0{0,0,0,0}, acc1{0,0,0,0};
  const __bf16* Ar = X + (size_t)(blk * 16 + c16) * 5376 + kh * 1344;
  const __bf16* B0 = Wb + (size_t)((2 * wc) * 16 + c16) * 5376 + kh * 1344;
  const __bf16* B1 = Wb + (size_t)((2 * wc + 1) * 16 + c16) * 5376 + kh * 1344;
  bf16x8 ab[6], b0b[6], b1b[6];
#pragma unroll
  for (int d = 0; d < 6; ++d) {
    int ko = d * 32 + quad * 8;
    ab[d] = ld8(Ar + ko); b0b[d] = ld8(B0 + ko); b1b[d] = ld8(B1 + ko);
  }
#pragma unroll
  for (int ks = 0; ks < 42; ++ks) {
    const int cur = ks % 6;
    acc0 = MFMA(ab[cur], b0b[cur], acc0);
    acc1 = MFMA(ab[cur], b1b[cur], acc1);
    if (ks + 6 < 42) {
      int ko = (ks + 6) * 32 + quad * 8;
      ab[cur] = ld8(Ar + ko); b0b[cur] = ld8(B0 + ko); b1b[cur] = ld8(B1 + ko);
    }
  }
#pragma unroll
  for (int nt = 0; nt < 2; ++nt) {
    f32x4 av = nt ? acc1 : acc0;
#pragma unroll
    for (int r = 0; r < 4; ++r) cout[(kh * 16 + quad * 4 + r) * 132 + (2 * wc + nt) * 16 + c16] = av[r];
  }
  __syncthreads();
  if (w2 < 4) {
#pragma unroll
    for (int rr = 0; rr < 4; ++rr) {
      int row = w2 * 4 + rr;
      float v0 = cout[row * 132 + lane] + cout[(16 + row) * 132 + lane] +
                 cout[(32 + row) * 132 + lane] + cout[(48 + row) * 132 + lane] + b_out[lane];
      float v1 = cout[row * 132 + 64 + lane] + cout[(16 + row) * 132 + 64 + lane] +
                 cout[(32 + row) * 132 + 64 + lane] + cout[(48 + row) * 132 + 64 + lane] + b_out[64 + lane];
      float s = v0 + v1, ss = v0 * v0 + v1 * v1;
#pragma unroll
      for (int m = 1; m < 64; m <<= 1) { s += __shfl_xor(s, m); ss += __shfl_xor(ss, m); }
      float mu = s * 0.0078125f;
      float var = fmaxf(ss * 0.0078125f - mu * mu, 0.f);
      float rs = rsqrtf(var + 1e-5f);
      size_t o = (size_t)(blk * 16 + row) * 128;
      out[o + lane] = (v0 - mu) * rs * lnf_g[lane] + lnf_b[lane];
      out[o + 64 + lane] = (v1 - mu) * rs * lnf_g[64 + lane] + lnf_b[64 + lane];
    }
  }
}

extern "C" void kernel_launch(void* const* d_in, const int* in_sizes, int n_in,
                              void* d_out, int out_size, void* d_ws, size_t ws_size,
                              hipStream_t stream) {
  const float* forest     = (const float*)d_in[0];
  const int*   adjacency  = (const int*)d_in[1];
  const int*   node_order = (const int*)d_in[2];
  const float* W_in       = (const float*)d_in[3];
  const float* b_in       = (const float*)d_in[4];
  const float* qkv_b      = (const float*)d_in[6];
  const float* ao_b       = (const float*)d_in[8];
  const float* ff1_b      = (const float*)d_in[10];
  const float* ff2_b      = (const float*)d_in[12];
  const float* ln1_g      = (const float*)d_in[13];
  const float* ln1_b      = (const float*)d_in[14];
  const float* ln2_g      = (const float*)d_in[15];
  const float* ln2_b      = (const float*)d_in[16];
  const float* b_out      = (const float*)d_in[18];
  const float* lnf_g      = (const float*)d_in[19];
  const float* lnf_b      = (const float*)d_in[20];
  __bf16* wb = (__bf16*)d_ws;
  float* out = (float*)d_out;

  prep_bf16<<<dim3(PREP_N / 256), dim3(256), 0, stream>>>(
      W_in, (const float*)d_in[5], (const float*)d_in[7], (const float*)d_in[9],
      (const float*)d_in[11], (const float*)d_in[17], wb);
  tree_enc<<<dim3(FB_ / 2), dim3(512), 0, stream>>>(forest, adjacency, node_order, b_in, qkv_b,
                                                    ao_b, ff1_b, ff2_b, ln1_g, ln1_b, ln2_g,
                                                    ln2_b, wb, wb + WB_X);
  wout_k<<<dim3(FB_ / 16), dim3(1024), 0, stream>>>(wb + WB_X, wb + WB_WOUT, b_out, lnf_g, lnf_b,
                                                    out);
}